// Round 2
// 139.140 us; speedup vs baseline: 1.0133x; 1.0133x over previous
//
#include <hip/hip_runtime.h>
#include <math.h>

// Problem constants (match reference).
constexpr int kN      = 5;
constexpr int kB      = 1048576;
constexpr int kBN     = kB * kN;        // 5242880 elements per output plane
constexpr int kBN4    = kBN / 4;        // 1310720 float4 groups per plane
constexpr int kSteps  = 10;
constexpr int kBlocks = 1280;           // 5 blocks/CU
constexpr int kThreads = 256;
constexpr unsigned kStride  = kBlocks * kThreads;   // 327680 — divisible by 5 (65536*5)!
constexpr int      kIters   = kBN4 / kStride;       // exactly 4, no tail
constexpr unsigned kStrideB = 4u * kStride / 5u;    // 262144 — integral b-advance per iter

static_assert(kStride % 5u == 0, "grid stride must be 0 mod 5 for loop-invariant phase");
static_assert(kIters * kStride == (unsigned)kBN4, "exact coverage, no bounds check needed");

// Native vector type — __builtin_nontemporal_store requires a clang ext-vector,
// not HIP's float4 class.
typedef float floatx4 __attribute__((ext_vector_type(4)));

// One dynamics evaluation. Lane i (within wave 0) owns oscillator i; lanes 5..63
// mirror lane 0 (results ignored) so all 64 lanes participate in the shuffles.
__device__ __forceinline__ void cpg_dynamics(float r, float rd, float th,
                                             float mu, float a,
                                             const float wr[kN], const float ph[kN],
                                             float freq, float& rdd, float& thd)
{
    rdd = a * (a * 0.25f * (mu - r) - rd);
    float coup = 0.f;
#pragma unroll
    for (int j = 0; j < kN; ++j) {
        float th_j = __shfl(th, j);
        float r_j  = __shfl(r, j);
        coup = __builtin_fmaf(wr[j] * __sinf(th_j - th - ph[j]), r_j, coup);
    }
    thd = freq + coup;
}

__device__ __forceinline__ float softplus_f(float x)
{
    // stable: max(x,0) + log1p(exp(-|x|))
    return fmaxf(x, 0.f) + log1pf(expf(-fabsf(x)));
}

__global__ __launch_bounds__(kThreads)
void ijspeert_kernel(const float* __restrict__ t,
                     const float* __restrict__ dt_p,
                     const float* __restrict__ mu_p,
                     const float* __restrict__ a_p,
                     const float* __restrict__ w_p,
                     const float* __restrict__ phi_p,
                     const float* __restrict__ freq_p,
                     const float* __restrict__ amp_p,
                     const float* __restrict__ phase_p,
                     const float* __restrict__ std_p,
                     float* __restrict__ out)
{
    __shared__ float s_amp[kN], s_w2[kN], s_p[kN], s_std[kN], s_r[kN], s_th[kN];

    // ---- Preamble: batch-independent RK4 solve, wave 0 only, 5 live lanes ----
    if (threadIdx.x < 64) {
        const int i = (threadIdx.x < kN) ? (int)threadIdx.x : 0;
        const float dt = dt_p[0];
        const float mu = mu_p[i];
        const float a  = a_p[i];
        const float fr = freq_p[i];
        float wr[kN], ph[kN];
#pragma unroll
        for (int j = 0; j < kN; ++j) {
            wr[j] = w_p[i * kN + j];
            ph[j] = phi_p[i * kN + j];
        }

        float r = 0.f, rd = 0.f, th = 0.f;
        for (int s = 0; s < kSteps; ++s) {
            float rdd1, td1, rdd2, td2, rdd3, td3, rdd4, td4;
            cpg_dynamics(r, rd, th, mu, a, wr, ph, fr, rdd1, td1);
            const float k1_r = rd, k1_rd = rdd1, k1_t = td1;
            cpg_dynamics(r + 0.5f * dt * k1_r, rd + 0.5f * dt * k1_rd,
                         th + 0.5f * dt * k1_t, mu, a, wr, ph, fr, rdd2, td2);
            const float k2_r = rd + 0.5f * dt * k1_rd, k2_rd = rdd2, k2_t = td2;
            cpg_dynamics(r + 0.5f * dt * k2_r, rd + 0.5f * dt * k2_rd,
                         th + 0.5f * dt * k2_t, mu, a, wr, ph, fr, rdd3, td3);
            const float k3_r = rd + 0.5f * dt * k2_rd, k3_rd = rdd3, k3_t = td3;
            cpg_dynamics(r + dt * k3_r, rd + dt * k3_rd,
                         th + dt * k3_t, mu, a, wr, ph, fr, rdd4, td4);
            const float k4_r = rd + dt * k3_rd, k4_rd = rdd4, k4_t = td4;
            const float c = dt * (1.f / 6.f);
            r  += c * (k1_r  + 2.f * k2_r  + 2.f * k3_r  + k4_r);
            rd += c * (k1_rd + 2.f * k2_rd + 2.f * k3_rd + k4_rd);
            th += c * (k1_t  + 2.f * k2_t  + 2.f * k3_t  + k4_t);
        }

        if (threadIdx.x < kN) {
            const float pi  = 3.14159265358979323846f;
            const float rng = (i & 1) ? pi : (0.5f * pi);   // RANGE = {pi/2,pi,pi/2,pi,pi/2}
            const float f_true = softplus_f(fr);
            s_w2[i]  = 2.f * pi * f_true;
            s_amp[i] = tanhf(amp_p[i]) * rng;
            s_p[i]   = softplus_f(phase_p[i]);
            s_std[i] = std_p[i];
            s_r[i]   = r;
            s_th[i]  = th;
        }
    }
    __syncthreads();

    // ---- Streaming epilogue ----
    // Key invariant: kStride % 5 == 0, so each thread's phase m = (4*q) mod 5 is
    // loop-invariant. Element k of group q is (b0 + (m+k>=5), (m+k) mod 5), with
    // b0 advancing by the compile-time constant kStrideB per iteration.
    // => all 6 per-oscillator tables hoist to registers ONCE; the std/r/theta
    //    planes become constant float4 register stores; no div/mod in the loop.
    const unsigned gid = blockIdx.x * kThreads + threadIdx.x;
    const unsigned m   = (4u * gid) % 5u;          // loop-invariant phase
    unsigned b = (4u * gid - m) / 5u;              // base batch index
    unsigned q = gid;

    float ampk[4], w2k[4], pk[4];
    floatx4 vs, vr4, vt4;
#pragma unroll
    for (int k = 0; k < 4; ++k) {
        unsigned ik = m + (unsigned)k;
        if (ik >= 5u) ik -= 5u;
        ampk[k] = s_amp[ik];
        w2k[k]  = s_w2[ik];
        pk[k]   = s_p[ik];
        vs[k]   = s_std[ik];
        vr4[k]  = s_r[ik];
        vt4[k]  = s_th[ik];
    }

    floatx4* o = reinterpret_cast<floatx4*>(out);

#pragma unroll
    for (int it = 0; it < kIters; ++it) {
        const float t0 = t[b];
        const unsigned b1 = (b + 1u < (unsigned)kB) ? (b + 1u) : (unsigned)(kB - 1);
        const float t1 = t[b1];                    // value unused when m+k<5 for all k

        floatx4 vm;
#pragma unroll
        for (int k = 0; k < 4; ++k) {
            const float tb = ((m + (unsigned)k) >= 5u) ? t1 : t0;   // one v_cndmask
            vm[k] = ampk[k] * __sinf(__builtin_fmaf(w2k[k], tb, pk[k]));
        }

        // Write-once 84 MB stream: non-temporal to avoid L2 thrash.
        __builtin_nontemporal_store(vm,  &o[q]);
        __builtin_nontemporal_store(vs,  &o[kBN4 + q]);
        __builtin_nontemporal_store(vr4, &o[2 * kBN4 + q]);
        __builtin_nontemporal_store(vt4, &o[3 * kBN4 + q]);

        q += kStride;
        b += kStrideB;
    }
}

extern "C" void kernel_launch(void* const* d_in, const int* in_sizes, int n_in,
                              void* d_out, int out_size, void* d_ws, size_t ws_size,
                              hipStream_t stream)
{
    // setup_inputs order:
    // 0: obs [B,10] (unused)   1: t [B]        2: dt [1]
    // 3: mu_p [N]  4: a [N]    5: w [N,N]      6: phi [N,N]
    // 7: frequencies [N]  8: amplitudes [N]  9: phases [N]  10: std [N]
    const float* t      = (const float*)d_in[1];
    const float* dt     = (const float*)d_in[2];
    const float* mu_p   = (const float*)d_in[3];
    const float* a      = (const float*)d_in[4];
    const float* w      = (const float*)d_in[5];
    const float* phi    = (const float*)d_in[6];
    const float* freq   = (const float*)d_in[7];
    const float* amp    = (const float*)d_in[8];
    const float* phase  = (const float*)d_in[9];
    const float* stdv   = (const float*)d_in[10];
    float* out = (float*)d_out;

    ijspeert_kernel<<<kBlocks, kThreads, 0, stream>>>(
        t, dt, mu_p, a, w, phi, freq, amp, phase, stdv, out);
}

// Round 3
// 131.521 us; speedup vs baseline: 1.0720x; 1.0579x over previous
//
#include <hip/hip_runtime.h>
#include <math.h>

// Problem constants (match reference).
constexpr int kN      = 5;
constexpr int kB      = 1048576;
constexpr int kBN     = kB * kN;        // 5242880 elements per output plane
constexpr int kBN4    = kBN / 4;        // 1310720 float4 groups per plane
constexpr int kSteps  = 10;
constexpr int kThreads = 256;

// Plane-specialized grid: 4 groups of 320 blocks, one group per output plane.
// Each block writes ONE contiguous stream (fill-kernel access pattern).
constexpr int kBlocksPerPlane = 320;
constexpr int kBlocksTotal    = 4 * kBlocksPerPlane;        // 1280 = 5 blocks/CU, co-resident
constexpr unsigned kPlaneThreads = kBlocksPerPlane * kThreads;  // 81920
constexpr int      kItersPP      = kBN4 / kPlaneThreads;        // 16, exact
constexpr unsigned kStrideB      = 4u * kPlaneThreads / 5u;     // 65536 — integral b-advance

static_assert((4u * kPlaneThreads) % 5u == 0, "phase must be loop-invariant");
static_assert(kItersPP * kPlaneThreads == (unsigned)kBN4, "exact coverage");

// Native vector type — __builtin_nontemporal_store requires a clang ext-vector.
typedef float floatx4 __attribute__((ext_vector_type(4)));

// One dynamics evaluation. Lane i (within wave 0) owns oscillator i; lanes 5..63
// mirror lane 0 (results ignored) so all 64 lanes participate in the shuffles.
__device__ __forceinline__ void cpg_dynamics(float r, float rd, float th,
                                             float mu, float a,
                                             const float wr[kN], const float ph[kN],
                                             float freq, float& rdd, float& thd)
{
    rdd = a * (a * 0.25f * (mu - r) - rd);
    float coup = 0.f;
#pragma unroll
    for (int j = 0; j < kN; ++j) {
        float th_j = __shfl(th, j);
        float r_j  = __shfl(r, j);
        coup = __builtin_fmaf(wr[j] * __sinf(th_j - th - ph[j]), r_j, coup);
    }
    thd = freq + coup;
}

__device__ __forceinline__ float softplus_f(float x)
{
    // stable: max(x,0) + log1p(exp(-|x|))
    return fmaxf(x, 0.f) + log1pf(expf(-fabsf(x)));
}

__global__ __launch_bounds__(kThreads)
void ijspeert_kernel(const float* __restrict__ t,
                     const float* __restrict__ dt_p,
                     const float* __restrict__ mu_p,
                     const float* __restrict__ a_p,
                     const float* __restrict__ w_p,
                     const float* __restrict__ phi_p,
                     const float* __restrict__ freq_p,
                     const float* __restrict__ amp_p,
                     const float* __restrict__ phase_p,
                     const float* __restrict__ std_p,
                     float* __restrict__ out)
{
    const int plane = blockIdx.x / kBlocksPerPlane;   // 0:mu 1:std 2:r 3:theta
    const int pblk  = blockIdx.x % kBlocksPerPlane;
    const unsigned ql = (unsigned)pblk * kThreads + threadIdx.x;  // 0..81919

    // Loop-invariant phase: element k of group q is oscillator (m+k) mod 5 of
    // batch b0 + (m+k>=5), with b0 advancing by the constant kStrideB per iter.
    const unsigned m = (4u * ql) % 5u;
    unsigned b = (4u * ql - m) / 5u;
    unsigned q = ql;

    unsigned ik[4];
#pragma unroll
    for (int k = 0; k < 4; ++k) {
        unsigned v = m + (unsigned)k;
        ik[k] = (v >= 5u) ? (v - 5u) : v;
    }

    floatx4* o = reinterpret_cast<floatx4*>(out) + (size_t)plane * kBN4;

    if (plane == 0) {
        // ---- mu plane: amp*sin(2*pi*f*t + p). No RK4 needed. ----
        const float pi = 3.14159265358979323846f;
        float ampk[4], w2k[4], pk[4];
#pragma unroll
        for (int k = 0; k < 4; ++k) {
            const unsigned i = ik[k];
            const float rng = (i & 1u) ? pi : (0.5f * pi);  // RANGE = {pi/2,pi,pi/2,pi,pi/2}
            ampk[k] = tanhf(amp_p[i]) * rng;
            w2k[k]  = 2.f * pi * softplus_f(freq_p[i]);
            pk[k]   = softplus_f(phase_p[i]);
        }
#pragma unroll
        for (int it = 0; it < kItersPP; ++it) {
            const float t0 = t[b];
            const unsigned b1 = (b + 1u < (unsigned)kB) ? (b + 1u) : (unsigned)(kB - 1);
            const float t1 = t[b1];  // used only for elements with m+k>=5
            floatx4 vm;
#pragma unroll
            for (int k = 0; k < 4; ++k) {
                const float tb = ((m + (unsigned)k) >= 5u) ? t1 : t0;
                vm[k] = ampk[k] * __sinf(__builtin_fmaf(w2k[k], tb, pk[k]));
            }
            __builtin_nontemporal_store(vm, &o[q]);
            q += kPlaneThreads;
            b += kStrideB;
        }
    } else if (plane == 1) {
        // ---- std plane: pure splat fill. ----
        floatx4 vs;
#pragma unroll
        for (int k = 0; k < 4; ++k) vs[k] = std_p[ik[k]];
#pragma unroll
        for (int it = 0; it < kItersPP; ++it) {
            __builtin_nontemporal_store(vs, &o[q]);
            q += kPlaneThreads;
        }
    } else {
        // ---- r / theta planes: RK4 once per block (wave 0), then splat fill. ----
        __shared__ float s_r[kN], s_th[kN];
        if (threadIdx.x < 64) {
            const int i = (threadIdx.x < kN) ? (int)threadIdx.x : 0;
            const float dt = dt_p[0];
            const float mu = mu_p[i];
            const float a  = a_p[i];
            const float fr = freq_p[i];
            float wr[kN], ph[kN];
#pragma unroll
            for (int j = 0; j < kN; ++j) {
                wr[j] = w_p[i * kN + j];
                ph[j] = phi_p[i * kN + j];
            }

            float r = 0.f, rd = 0.f, th = 0.f;
            for (int s = 0; s < kSteps; ++s) {
                float rdd1, td1, rdd2, td2, rdd3, td3, rdd4, td4;
                cpg_dynamics(r, rd, th, mu, a, wr, ph, fr, rdd1, td1);
                const float k1_r = rd, k1_rd = rdd1, k1_t = td1;
                cpg_dynamics(r + 0.5f * dt * k1_r, rd + 0.5f * dt * k1_rd,
                             th + 0.5f * dt * k1_t, mu, a, wr, ph, fr, rdd2, td2);
                const float k2_r = rd + 0.5f * dt * k1_rd, k2_rd = rdd2, k2_t = td2;
                cpg_dynamics(r + 0.5f * dt * k2_r, rd + 0.5f * dt * k2_rd,
                             th + 0.5f * dt * k2_t, mu, a, wr, ph, fr, rdd3, td3);
                const float k3_r = rd + 0.5f * dt * k2_rd, k3_rd = rdd3, k3_t = td3;
                cpg_dynamics(r + dt * k3_r, rd + dt * k3_rd,
                             th + dt * k3_t, mu, a, wr, ph, fr, rdd4, td4);
                const float k4_r = rd + dt * k3_rd, k4_rd = rdd4, k4_t = td4;
                const float c = dt * (1.f / 6.f);
                r  += c * (k1_r  + 2.f * k2_r  + 2.f * k3_r  + k4_r);
                rd += c * (k1_rd + 2.f * k2_rd + 2.f * k3_rd + k4_rd);
                th += c * (k1_t  + 2.f * k2_t  + 2.f * k3_t  + k4_t);
            }
            if (threadIdx.x < kN) { s_r[i] = r; s_th[i] = th; }
        }
        __syncthreads();

        const float* src = (plane == 2) ? s_r : s_th;
        floatx4 v;
#pragma unroll
        for (int k = 0; k < 4; ++k) v[k] = src[ik[k]];
#pragma unroll
        for (int it = 0; it < kItersPP; ++it) {
            __builtin_nontemporal_store(v, &o[q]);
            q += kPlaneThreads;
        }
    }
}

extern "C" void kernel_launch(void* const* d_in, const int* in_sizes, int n_in,
                              void* d_out, int out_size, void* d_ws, size_t ws_size,
                              hipStream_t stream)
{
    // setup_inputs order:
    // 0: obs [B,10] (unused)   1: t [B]        2: dt [1]
    // 3: mu_p [N]  4: a [N]    5: w [N,N]      6: phi [N,N]
    // 7: frequencies [N]  8: amplitudes [N]  9: phases [N]  10: std [N]
    const float* t      = (const float*)d_in[1];
    const float* dt     = (const float*)d_in[2];
    const float* mu_p   = (const float*)d_in[3];
    const float* a      = (const float*)d_in[4];
    const float* w      = (const float*)d_in[5];
    const float* phi    = (const float*)d_in[6];
    const float* freq   = (const float*)d_in[7];
    const float* amp    = (const float*)d_in[8];
    const float* phase  = (const float*)d_in[9];
    const float* stdv   = (const float*)d_in[10];
    float* out = (float*)d_out;

    ijspeert_kernel<<<kBlocksTotal, kThreads, 0, stream>>>(
        t, dt, mu_p, a, w, phi, freq, amp, phase, stdv, out);
}

// Round 4
// 130.817 us; speedup vs baseline: 1.0777x; 1.0054x over previous
//
#include <hip/hip_runtime.h>
#include <math.h>

// Problem constants (match reference).
constexpr int kN      = 5;
constexpr int kB      = 1048576;
constexpr int kBN     = kB * kN;        // 5242880 elements per output plane
constexpr int kBN4    = kBN / 4;        // 1310720 float4 groups per plane
constexpr int kSteps  = 10;
constexpr int kThreads = 256;

// Plane-specialized grid: 4 groups of 320 blocks, one group per output plane.
// Each block writes ONE contiguous-chunk grid-stride stream (fill-kernel pattern).
constexpr int kBlocksPerPlane = 320;
constexpr int kBlocksTotal    = 4 * kBlocksPerPlane;        // 1280 = 5 blocks/CU, co-resident
constexpr unsigned kPlaneThreads = kBlocksPerPlane * kThreads;  // 81920
constexpr int      kItersPP      = kBN4 / kPlaneThreads;        // 16, exact
constexpr unsigned kStrideB      = 4u * kPlaneThreads / 5u;     // 65536 — integral b-advance

static_assert((4u * kPlaneThreads) % 5u == 0, "phase must be loop-invariant");
static_assert(kItersPP * kPlaneThreads == (unsigned)kBN4, "exact coverage");

// Native 16-B vector type (layout-identical to float4).
typedef float floatx4 __attribute__((ext_vector_type(4)));

// One dynamics evaluation. Lane i (within wave 0) owns oscillator i; lanes 5..63
// mirror lane 0 (results ignored) so all 64 lanes participate in the shuffles.
__device__ __forceinline__ void cpg_dynamics(float r, float rd, float th,
                                             float mu, float a,
                                             const float wr[kN], const float ph[kN],
                                             float freq, float& rdd, float& thd)
{
    rdd = a * (a * 0.25f * (mu - r) - rd);
    float coup = 0.f;
#pragma unroll
    for (int j = 0; j < kN; ++j) {
        float th_j = __shfl(th, j);
        float r_j  = __shfl(r, j);
        coup = __builtin_fmaf(wr[j] * __sinf(th_j - th - ph[j]), r_j, coup);
    }
    thd = freq + coup;
}

__device__ __forceinline__ float softplus_f(float x)
{
    // stable: max(x,0) + log1p(exp(-|x|))
    return fmaxf(x, 0.f) + log1pf(expf(-fabsf(x)));
}

__global__ __launch_bounds__(kThreads)
void ijspeert_kernel(const float* __restrict__ t,
                     const float* __restrict__ dt_p,
                     const float* __restrict__ mu_p,
                     const float* __restrict__ a_p,
                     const float* __restrict__ w_p,
                     const float* __restrict__ phi_p,
                     const float* __restrict__ freq_p,
                     const float* __restrict__ amp_p,
                     const float* __restrict__ phase_p,
                     const float* __restrict__ std_p,
                     float* __restrict__ out)
{
    const int plane = blockIdx.x / kBlocksPerPlane;   // 0:mu 1:std 2:r 3:theta
    const int pblk  = blockIdx.x % kBlocksPerPlane;
    const unsigned ql = (unsigned)pblk * kThreads + threadIdx.x;  // 0..81919

    // Loop-invariant phase: element k of group q is oscillator (m+k) mod 5 of
    // batch b0 + (m+k>=5), with b0 advancing by the constant kStrideB per iter.
    const unsigned m = (4u * ql) % 5u;
    unsigned b = (4u * ql - m) / 5u;
    unsigned q = ql;

    unsigned ik[4];
#pragma unroll
    for (int k = 0; k < 4; ++k) {
        unsigned v = m + (unsigned)k;
        ik[k] = (v >= 5u) ? (v - 5u) : v;
    }

    floatx4* o = reinterpret_cast<floatx4*>(out) + (size_t)plane * kBN4;

    if (plane == 0) {
        // ---- mu plane: amp*sin(2*pi*f*t + p). No RK4 needed. ----
        const float pi = 3.14159265358979323846f;
        float ampk[4], w2k[4], pk[4];
#pragma unroll
        for (int k = 0; k < 4; ++k) {
            const unsigned i = ik[k];
            const float rng = (i & 1u) ? pi : (0.5f * pi);  // RANGE = {pi/2,pi,pi/2,pi,pi/2}
            ampk[k] = tanhf(amp_p[i]) * rng;
            w2k[k]  = 2.f * pi * softplus_f(freq_p[i]);
            pk[k]   = softplus_f(phase_p[i]);
        }
#pragma unroll
        for (int it = 0; it < kItersPP; ++it) {
            const float t0 = t[b];
            const unsigned b1 = (b + 1u < (unsigned)kB) ? (b + 1u) : (unsigned)(kB - 1);
            const float t1 = t[b1];  // used only for elements with m+k>=5
            floatx4 vm;
#pragma unroll
            for (int k = 0; k < 4; ++k) {
                const float tb = ((m + (unsigned)k) >= 5u) ? t1 : t0;
                vm[k] = ampk[k] * __sinf(__builtin_fmaf(w2k[k], tb, pk[k]));
            }
            o[q] = vm;                       // plain store (A/B vs round-3 nt store)
            q += kPlaneThreads;
            b += kStrideB;
        }
    } else if (plane == 1) {
        // ---- std plane: pure splat fill. ----
        floatx4 vs;
#pragma unroll
        for (int k = 0; k < 4; ++k) vs[k] = std_p[ik[k]];
#pragma unroll
        for (int it = 0; it < kItersPP; ++it) {
            o[q] = vs;                       // plain store
            q += kPlaneThreads;
        }
    } else {
        // ---- r / theta planes: RK4 once per block (wave 0), then splat fill. ----
        __shared__ float s_r[kN], s_th[kN];
        if (threadIdx.x < 64) {
            const int i = (threadIdx.x < kN) ? (int)threadIdx.x : 0;
            const float dt = dt_p[0];
            const float mu = mu_p[i];
            const float a  = a_p[i];
            const float fr = freq_p[i];
            float wr[kN], ph[kN];
#pragma unroll
            for (int j = 0; j < kN; ++j) {
                wr[j] = w_p[i * kN + j];
                ph[j] = phi_p[i * kN + j];
            }

            float r = 0.f, rd = 0.f, th = 0.f;
            for (int s = 0; s < kSteps; ++s) {
                float rdd1, td1, rdd2, td2, rdd3, td3, rdd4, td4;
                cpg_dynamics(r, rd, th, mu, a, wr, ph, fr, rdd1, td1);
                const float k1_r = rd, k1_rd = rdd1, k1_t = td1;
                cpg_dynamics(r + 0.5f * dt * k1_r, rd + 0.5f * dt * k1_rd,
                             th + 0.5f * dt * k1_t, mu, a, wr, ph, fr, rdd2, td2);
                const float k2_r = rd + 0.5f * dt * k1_rd, k2_rd = rdd2, k2_t = td2;
                cpg_dynamics(r + 0.5f * dt * k2_r, rd + 0.5f * dt * k2_rd,
                             th + 0.5f * dt * k2_t, mu, a, wr, ph, fr, rdd3, td3);
                const float k3_r = rd + 0.5f * dt * k2_rd, k3_rd = rdd3, k3_t = td3;
                cpg_dynamics(r + dt * k3_r, rd + dt * k3_rd,
                             th + dt * k3_t, mu, a, wr, ph, fr, rdd4, td4);
                const float k4_r = rd + dt * k3_rd, k4_rd = rdd4, k4_t = td4;
                const float c = dt * (1.f / 6.f);
                r  += c * (k1_r  + 2.f * k2_r  + 2.f * k3_r  + k4_r);
                rd += c * (k1_rd + 2.f * k2_rd + 2.f * k3_rd + k4_rd);
                th += c * (k1_t  + 2.f * k2_t  + 2.f * k3_t  + k4_t);
            }
            if (threadIdx.x < kN) { s_r[i] = r; s_th[i] = th; }
        }
        __syncthreads();

        const float* src = (plane == 2) ? s_r : s_th;
        floatx4 v;
#pragma unroll
        for (int k = 0; k < 4; ++k) v[k] = src[ik[k]];
#pragma unroll
        for (int it = 0; it < kItersPP; ++it) {
            o[q] = v;                        // plain store
            q += kPlaneThreads;
        }
    }
}

extern "C" void kernel_launch(void* const* d_in, const int* in_sizes, int n_in,
                              void* d_out, int out_size, void* d_ws, size_t ws_size,
                              hipStream_t stream)
{
    // setup_inputs order:
    // 0: obs [B,10] (unused)   1: t [B]        2: dt [1]
    // 3: mu_p [N]  4: a [N]    5: w [N,N]      6: phi [N,N]
    // 7: frequencies [N]  8: amplitudes [N]  9: phases [N]  10: std [N]
    const float* t      = (const float*)d_in[1];
    const float* dt     = (const float*)d_in[2];
    const float* mu_p   = (const float*)d_in[3];
    const float* a      = (const float*)d_in[4];
    const float* w      = (const float*)d_in[5];
    const float* phi    = (const float*)d_in[6];
    const float* freq   = (const float*)d_in[7];
    const float* amp    = (const float*)d_in[8];
    const float* phase  = (const float*)d_in[9];
    const float* stdv   = (const float*)d_in[10];
    float* out = (float*)d_out;

    ijspeert_kernel<<<kBlocksTotal, kThreads, 0, stream>>>(
        t, dt, mu_p, a, w, phi, freq, amp, phase, stdv, out);
}